// Round 1
// baseline (1205.895 us; speedup 1.0000x reference)
//
#include <hip/hip_runtime.h>
#include <math.h>

#define N_ROWS 262144
#define KCODES 512
#define DIM 64
#define BLOCK 256

// Output layout (flat fp32, reference return order):
//   [0]                      loss (scalar)
//   [1 .. 1+N*64)            quantized
//   [1+N*64]                 perplexity (=1.0)
//   [2+N*64 .. +N*512)       encodings (one-hot)
//   [... .. +N)              encoding_indices (as float)
static const size_t OFF_LOSS = 0;
static const size_t OFF_Q    = 1;
static const size_t OFF_PERP = 1 + (size_t)N_ROWS * DIM;
static const size_t OFF_ENC  = OFF_PERP + 1;
static const size_t OFF_IDX  = OFF_ENC + (size_t)N_ROWS * KCODES;

// Kernel 1: L2-normalize embedding rows into workspace; init scalar outputs.
__global__ __launch_bounds__(64) void vq_prep(const float* __restrict__ emb,
                                              float* __restrict__ embn,
                                              float* __restrict__ out_loss,
                                              float* __restrict__ out_perp) {
    int k = blockIdx.x;
    int d = threadIdx.x;
    float v = emb[k * DIM + d];
    float s = v * v;
    #pragma unroll
    for (int off = 32; off > 0; off >>= 1) s += __shfl_xor(s, off, 64);
    float scale = 1.0f / fmaxf(sqrtf(s), 1e-12f);
    embn[k * DIM + d] = v * scale;
    if (k == 0 && d == 0) {
        *out_loss = 0.0f;
        *out_perp = 1.0f;
    }
}

// Kernel 2: one row per thread. Row lives in 64 VGPRs; codebook rows are read
// through wave-uniform addresses so the compiler can promote them to s_load
// (SGPR operands into v_fmac — no per-lane VMEM in the hot loop).
__global__ __launch_bounds__(BLOCK) void vq_main(const float* __restrict__ x,
                                                 const int* __restrict__ labels,
                                                 const float* __restrict__ emb,
                                                 const float* __restrict__ embn,
                                                 float* __restrict__ out_loss,
                                                 float* __restrict__ out_q,
                                                 float* __restrict__ out_enc,
                                                 float* __restrict__ out_idx) {
    const int row  = blockIdx.x * BLOCK + threadIdx.x;
    const int lane = threadIdx.x & 63;

    // Load this thread's row (contiguous 256 B; 16 dwordx4 loads).
    float xr[DIM];
    const float4* xv = (const float4*)(x + (size_t)row * DIM);
    #pragma unroll
    for (int i = 0; i < DIM / 4; ++i) ((float4*)xr)[i] = xv[i];

    float nx2 = 0.f;
    #pragma unroll
    for (int d = 0; d < DIM; ++d) nx2 = fmaf(xr[d], xr[d], nx2);
    const float inv_nx = 1.0f / fmaxf(sqrtf(nx2), 1e-12f);

    const int lbl = labels[row];

    // argmax over dot(x, embn_k): scaling by inv_nx doesn't change ordering.
    float best = -3.4e38f;
    int   bidx = 0;
    float pick = 0.f;
    #pragma unroll 2
    for (int k = 0; k < KCODES; ++k) {
        const float* __restrict__ e = embn + k * DIM;  // wave-uniform address
        float a0 = 0.f, a1 = 0.f, a2 = 0.f, a3 = 0.f;
        #pragma unroll
        for (int d = 0; d < DIM; d += 4) {
            a0 = fmaf(xr[d + 0], e[d + 0], a0);
            a1 = fmaf(xr[d + 1], e[d + 1], a1);
            a2 = fmaf(xr[d + 2], e[d + 2], a2);
            a3 = fmaf(xr[d + 3], e[d + 3], a3);
        }
        float dot = (a0 + a1) + (a2 + a3);
        if (dot > best) { best = dot; bidx = k; }  // strict > keeps FIRST max (jnp.argmax)
        pick = (k == lbl) ? dot : pick;
    }

    // quantized = RAW embedding row at argmax (reference multiplies one-hot by emb).
    {
        const float4* ev = (const float4*)(emb + (size_t)bidx * DIM);
        float4* qv = (float4*)(out_q + (size_t)row * DIM);
        #pragma unroll
        for (int i = 0; i < DIM / 4; ++i) qv[i] = ev[i];
    }

    out_idx[row] = (float)bidx;

    // encodings: wave-cooperative, fully coalesced float4 stores.
    // Each iteration r: all 64 lanes write row (wrow0+r): cols [lane*4) and [256+lane*4).
    {
        const int wrow0 = row - lane;
        for (int r = 0; r < 64; ++r) {
            int bi = __shfl(bidx, r, 64);
            float* base = out_enc + (size_t)(wrow0 + r) * KCODES;
            int c0 = lane * 4;
            float4 v0 = make_float4(bi == c0     ? 1.f : 0.f,
                                    bi == c0 + 1 ? 1.f : 0.f,
                                    bi == c0 + 2 ? 1.f : 0.f,
                                    bi == c0 + 3 ? 1.f : 0.f);
            *(float4*)(base + c0) = v0;
            int c1 = 256 + lane * 4;
            float4 v1 = make_float4(bi == c1     ? 1.f : 0.f,
                                    bi == c1 + 1 ? 1.f : 0.f,
                                    bi == c1 + 2 ? 1.f : 0.f,
                                    bi == c1 + 3 ? 1.f : 0.f);
            *(float4*)(base + c1) = v1;
        }
    }

    // loss = mean(1 - distances[i, label_i]); distance needs x normalized.
    float lv = (1.0f - pick * inv_nx) * (1.0f / (float)N_ROWS);
    #pragma unroll
    for (int off = 32; off > 0; off >>= 1) lv += __shfl_xor(lv, off, 64);
    __shared__ float ls[BLOCK / 64];
    if (lane == 0) ls[threadIdx.x >> 6] = lv;
    __syncthreads();
    if (threadIdx.x == 0) {
        float s = 0.f;
        #pragma unroll
        for (int i = 0; i < BLOCK / 64; ++i) s += ls[i];
        atomicAdd(out_loss, s);
    }
}

extern "C" void kernel_launch(void* const* d_in, const int* in_sizes, int n_in,
                              void* d_out, int out_size, void* d_ws, size_t ws_size,
                              hipStream_t stream) {
    const float* x      = (const float*)d_in[0];
    const int*   labels = (const int*)d_in[1];
    const float* emb    = (const float*)d_in[2];
    float* out  = (float*)d_out;
    float* embn = (float*)d_ws;  // 512*64*4 = 128 KB

    hipLaunchKernelGGL(vq_prep, dim3(KCODES), dim3(64), 0, stream,
                       emb, embn, out + OFF_LOSS, out + OFF_PERP);
    hipLaunchKernelGGL(vq_main, dim3(N_ROWS / BLOCK), dim3(BLOCK), 0, stream,
                       x, labels, emb, embn,
                       out + OFF_LOSS, out + OFF_Q, out + OFF_ENC, out + OFF_IDX);
}

// Round 2
// 1005.182 us; speedup vs baseline: 1.1997x; 1.1997x over previous
//
#include <hip/hip_runtime.h>
#include <math.h>

#define N_ROWS 262144
#define KCODES 512
#define DIM 64
#define BLOCK 512            // threads per block; 1 row per thread
#define ROWS_PER_BLOCK BLOCK
#define KTILE 128            // codes per LDS tile (32 KB)
#define NTILES (KCODES / KTILE)

// Output layout (flat fp32, reference return order):
static const size_t OFF_LOSS = 0;
static const size_t OFF_Q    = 1;
static const size_t OFF_PERP = 1 + (size_t)N_ROWS * DIM;
static const size_t OFF_ENC  = OFF_PERP + 1;
static const size_t OFF_IDX  = OFF_ENC + (size_t)N_ROWS * KCODES;

// Kernel 1: L2-normalize embedding rows into workspace; init scalar outputs.
__global__ __launch_bounds__(64) void vq_prep(const float* __restrict__ emb,
                                              float* __restrict__ embn,
                                              float* __restrict__ out_loss,
                                              float* __restrict__ out_perp) {
    int k = blockIdx.x;
    int d = threadIdx.x;
    float v = emb[k * DIM + d];
    float s = v * v;
    #pragma unroll
    for (int off = 32; off > 0; off >>= 1) s += __shfl_xor(s, off, 64);
    float scale = 1.0f / fmaxf(sqrtf(s), 1e-12f);
    embn[k * DIM + d] = v * scale;
    if (k == 0 && d == 0) {
        *out_loss = 0.0f;
        *out_perp = 1.0f;
    }
}

// Kernel 2: one row per thread (row in 64 VGPRs). Codebook tiles staged in
// LDS; inner-loop reads are same-address broadcasts (no VMEM in hot loop).
// One-hot zeros are streamed out during compute; 1.0 scattered at the end.
__global__ __launch_bounds__(BLOCK) void vq_main(const float* __restrict__ x,
                                                 const int* __restrict__ labels,
                                                 const float* __restrict__ emb,
                                                 const float* __restrict__ embn,
                                                 float* __restrict__ out_loss,
                                                 float* __restrict__ out_q,
                                                 float* __restrict__ out_enc,
                                                 float* __restrict__ out_idx) {
    const int tid   = threadIdx.x;
    const int row   = blockIdx.x * ROWS_PER_BLOCK + tid;
    const int lane  = tid & 63;
    const int wrow0 = row - lane;                 // first row of this wave

    __shared__ float sE[KTILE * DIM];             // 32 KB codebook tile
    __shared__ float sLoss[BLOCK / 64];

    // Load this thread's row (contiguous 256 B).
    float xr[DIM];
    {
        const float4* xv = (const float4*)(x + (size_t)row * DIM);
        #pragma unroll
        for (int i = 0; i < DIM / 4; ++i) ((float4*)xr)[i] = xv[i];
    }

    float nx2 = 0.f;
    #pragma unroll
    for (int d = 0; d < DIM; ++d) nx2 = fmaf(xr[d], xr[d], nx2);
    const float inv_nx = 1.0f / fmaxf(sqrtf(nx2), 1e-12f);

    const int lbl = labels[row];

    float best = -3.4e38f;
    int   bidx = 0;
    float pick = 0.f;

    for (int t = 0; t < NTILES; ++t) {
        __syncthreads();
        // Cooperative tile load: 8192 floats; each thread moves 4 float4.
        {
            const float4* src = (const float4*)(embn + (size_t)t * KTILE * DIM);
            float4* dst = (float4*)sE;
            #pragma unroll
            for (int i = 0; i < (KTILE * DIM / 4) / BLOCK; ++i)
                dst[tid + i * BLOCK] = src[tid + i * BLOCK];
        }
        __syncthreads();

        // Streamed zero-fill of encodings cols [t*KTILE, t*KTILE+KTILE) for
        // this wave's 64 rows — contiguous 1 KB per instruction, overlaps FMA.
        {
            float* encb = out_enc + (size_t)wrow0 * KCODES + t * KTILE;
            const int rsub = lane >> 5;           // 0..1
            const int c    = (lane & 31) * 4;
            const float4 z = make_float4(0.f, 0.f, 0.f, 0.f);
            #pragma unroll
            for (int i = 0; i < 32; ++i)
                *(float4*)(encb + (size_t)(i * 2 + rsub) * KCODES + c) = z;
        }

        // Dot products against the LDS-resident tile.
        #pragma unroll 2
        for (int kk = 0; kk < KTILE; ++kk) {
            const float* e = sE + kk * DIM;       // wave-uniform → LDS broadcast
            float a0 = 0.f, a1 = 0.f, a2 = 0.f, a3 = 0.f;
            #pragma unroll
            for (int d = 0; d < DIM; d += 4) {
                a0 = fmaf(xr[d + 0], e[d + 0], a0);
                a1 = fmaf(xr[d + 1], e[d + 1], a1);
                a2 = fmaf(xr[d + 2], e[d + 2], a2);
                a3 = fmaf(xr[d + 3], e[d + 3], a3);
            }
            float dot = (a0 + a1) + (a2 + a3);
            int k = t * KTILE + kk;
            if (dot > best) { best = dot; bidx = k; }  // strict > = first max
            pick = (k == lbl) ? dot : pick;
        }
    }

    // quantized = raw embedding row at argmax — wave-cooperative, coalesced
    // (1 KB per store instruction; emb table is 128 KB, L2-resident).
    #pragma unroll
    for (int i = 0; i < 16; ++i) {
        const int r     = i * 4 + (lane >> 4);    // 0..63: row within wave
        const int chunk = lane & 15;              // float4 index within row
        const int bi    = __shfl(bidx, r, 64);
        float4 v = ((const float4*)(emb + (size_t)bi * DIM))[chunk];
        ((float4*)(out_q + (size_t)(wrow0 + r) * DIM))[chunk] = v;
    }

    out_idx[row] = (float)bidx;

    // loss = mean(1 - distances[i, label_i]).
    float lv = (1.0f - pick * inv_nx) * (1.0f / (float)N_ROWS);
    #pragma unroll
    for (int off = 32; off > 0; off >>= 1) lv += __shfl_xor(lv, off, 64);
    if (lane == 0) sLoss[tid >> 6] = lv;
    __syncthreads();
    if (tid == 0) {
        float s = 0.f;
        #pragma unroll
        for (int i = 0; i < BLOCK / 64; ++i) s += sLoss[i];
        atomicAdd(out_loss, s);
    }

    // Make sure this wave's zero-fill stores for our rows have completed,
    // then scatter the single 1.0 per row (same wave wrote the zeros).
    asm volatile("s_waitcnt vmcnt(0)" ::: "memory");
    out_enc[(size_t)row * KCODES + bidx] = 1.0f;
}

extern "C" void kernel_launch(void* const* d_in, const int* in_sizes, int n_in,
                              void* d_out, int out_size, void* d_ws, size_t ws_size,
                              hipStream_t stream) {
    const float* x      = (const float*)d_in[0];
    const int*   labels = (const int*)d_in[1];
    const float* emb    = (const float*)d_in[2];
    float* out  = (float*)d_out;
    float* embn = (float*)d_ws;  // 512*64*4 = 128 KB

    hipLaunchKernelGGL(vq_prep, dim3(KCODES), dim3(64), 0, stream,
                       emb, embn, out + OFF_LOSS, out + OFF_PERP);
    hipLaunchKernelGGL(vq_main, dim3(N_ROWS / ROWS_PER_BLOCK), dim3(BLOCK), 0, stream,
                       x, labels, emb, embn,
                       out + OFF_LOSS, out + OFF_Q, out + OFF_ENC, out + OFF_IDX);
}